// Round 16
// baseline (324.057 us; speedup 1.0000x reference)
//
#include <hip/hip_runtime.h>

#define DIM 512
#define NHEAD 8
#define HDIM 64
#define BATCH 4
#define SEQ 2048
#define MTOT (BATCH*SEQ)
#define SCALE 0.125f
#define LOG2E 1.4426950408889634f

typedef __bf16 bf16_t;
typedef __bf16 bf16x8 __attribute__((ext_vector_type(8)));
typedef __bf16 bf16x4 __attribute__((ext_vector_type(4)));
typedef __bf16 bf16x2 __attribute__((ext_vector_type(2)));
typedef float f32x4 __attribute__((ext_vector_type(4)));

#define ASYNC_COPY16(g, l) __builtin_amdgcn_global_load_lds( \
    (const __attribute__((address_space(1))) void*)(g),      \
    (__attribute__((address_space(3))) void*)(l), 16, 0, 0)

// ---------------- fused fp32 -> bf16 convert (x | w_qkv | w_proj) ----------------
#define NX_ELEM  (4194304)
#define NWQ_ELEM (786432)
#define NWP_ELEM (262144)
__global__ __launch_bounds__(256) void cvt_kernel(const float* __restrict__ x,
                                                  const float* __restrict__ wq,
                                                  const float* __restrict__ wp,
                                                  bf16_t* __restrict__ out) {
    int i = (blockIdx.x * 256 + threadIdx.x) * 4;
    const float* src;
    if (i < NX_ELEM)                 src = x  + i;
    else if (i < NX_ELEM + NWQ_ELEM) src = wq + (i - NX_ELEM);
    else                             src = wp + (i - NX_ELEM - NWQ_ELEM);
    float4 v = *reinterpret_cast<const float4*>(src);
    bf16x4 o;
    o[0] = (bf16_t)v.x; o[1] = (bf16_t)v.y; o[2] = (bf16_t)v.z; o[3] = (bf16_t)v.w;
    *reinterpret_cast<bf16x4*>(out + i) = o;
}

// ---------------- QKV GEMM (R15-identical) ----------------
__global__ __launch_bounds__(256) void gemm_qkv_kernel(
    const bf16_t* __restrict__ X, const bf16_t* __restrict__ W,
    const float* __restrict__ bias,
    bf16_t* __restrict__ Qo, bf16_t* __restrict__ Ko, bf16_t* __restrict__ Vto)
{
    __shared__ bf16_t smem[16384];
    bf16_t (*As)[64] = reinterpret_cast<bf16_t (*)[64]>(smem);
    bf16_t (*Bs)[64] = reinterpret_cast<bf16_t (*)[64]>(smem + 8192);
    unsigned int* Lw = reinterpret_cast<unsigned int*>(smem);
    const int tid = threadIdx.x;
    const int wave = tid >> 6, lane = tid & 63;
    const int lhi = lane >> 4, llo = lane & 15;
    const int o = blockIdx.x;
    const int x = o & 7, i0 = o >> 3;
    const int m0 = (x * 8 + (i0 & 7)) * 128;
    const int n0 = (i0 >> 3) * 128;
    const int wr = (wave >> 1) * 64, wc = (wave & 1) * 64;
    f32x4 acc[4][4] = {};

    const int srow = wave * 32 + (lane >> 3);
    const int scol = (lane & 7) * 8;
    const bf16_t* gA = X + (size_t)(m0 + srow) * DIM + scol;
    const bf16_t* gB = W + (size_t)(n0 + srow) * DIM + scol;

    for (int k0 = 0; k0 < DIM; k0 += 64) {
        #pragma unroll
        for (int p = 0; p < 4; ++p) {
            ASYNC_COPY16(gA + (size_t)p * 8 * DIM + k0, &As[wave*32 + p*8][0]);
            ASYNC_COPY16(gB + (size_t)p * 8 * DIM + k0, &Bs[wave*32 + p*8][0]);
        }
        __syncthreads();
        #pragma unroll
        for (int ks = 0; ks < 2; ++ks) {
            bf16x8 af[4], bfr[4];
            #pragma unroll
            for (int i = 0; i < 4; ++i)
                af[i] = *reinterpret_cast<const bf16x8*>(&As[wr + i*16 + llo][ks*32 + lhi*8]);
            #pragma unroll
            for (int j = 0; j < 4; ++j)
                bfr[j] = *reinterpret_cast<const bf16x8*>(&Bs[wc + j*16 + llo][ks*32 + lhi*8]);
            __builtin_amdgcn_s_setprio(1);
            #pragma unroll
            for (int i = 0; i < 4; ++i)
                #pragma unroll
                for (int j = 0; j < 4; ++j)
                    acc[i][j] = __builtin_amdgcn_mfma_f32_16x16x32_bf16(af[i], bfr[j], acc[i][j], 0, 0, 0);
            __builtin_amdgcn_s_setprio(0);
        }
        __syncthreads();
    }

    const int b = m0 >> 11, ns0 = m0 & 2047;

    if (n0 < 1024) {
        const float qscale = (n0 < 512) ? (SCALE * LOG2E) : 1.0f;
        bf16_t* __restrict__ dst = (n0 < 512) ? Qo : Ko;
        #pragma unroll
        for (int j = 0; j < 4; ++j) {
            int ddc = wc + j*16 + llo;
            float bv = bias[n0 + ddc];
            #pragma unroll
            for (int i = 0; i < 4; ++i)
                #pragma unroll
                for (int r = 0; r < 4; ++r) {
                    int ml = wr + i*16 + lhi*4 + r;
                    smem[ml * 128 + (ddc ^ (((ml >> 2) & 3) * 16))] =
                        (bf16_t)((acc[i][j][r] + bv) * qscale);
                }
        }
        __syncthreads();
        #pragma unroll
        for (int k = 0; k < 8; ++k) {
            int c = tid + k * 256;
            int row = c >> 4, colc = (c & 15) * 8;
            uint4 val = *reinterpret_cast<const uint4*>(
                &smem[row * 128 + (colc ^ (((row >> 2) & 3) * 16))]);
            int col = n0 + colc;
            int hh = (col >> 6) & 7, dd = col & 63;
            size_t bh = (size_t)(b * NHEAD + hh);
            *reinterpret_cast<uint4*>(dst + (bh * SEQ + ns0 + row) * HDIM + dd) = val;
        }
    } else {
        #pragma unroll
        for (int j = 0; j < 4; ++j) {
            int ddc = wc + j*16 + llo;
            float bv = bias[n0 + ddc];
            int xsw = (ddc & 7) * 4;
            #pragma unroll
            for (int i = 0; i < 4; ++i) {
                int dwb = (wr >> 1) + i*8 + lhi*2;
                #pragma unroll
                for (int r2 = 0; r2 < 2; ++r2) {
                    bf16x2 t;
                    t[0] = (bf16_t)(acc[i][j][2*r2]     + bv);
                    t[1] = (bf16_t)(acc[i][j][2*r2 + 1] + bv);
                    Lw[ddc * 64 + ((dwb + r2) ^ xsw)] = __builtin_bit_cast(unsigned int, t);
                }
            }
        }
        __syncthreads();
        const int hh_base = (n0 - 1024) >> 6;
        const int chunk = tid & 15;
        #pragma unroll
        for (int rd = 0; rd < 8; ++rd) {
            int ddc = rd * 16 + (tid >> 4);
            uint4 val = *reinterpret_cast<const uint4*>(
                &Lw[ddc * 64 + ((chunk * 4) ^ ((ddc & 7) * 4))]);
            int dd = ddc & 63;
            int hh = hh_base + (ddc >> 6);
            size_t bh = (size_t)(b * NHEAD + hh);
            *reinterpret_cast<uint4*>(Vto + (bh * HDIM + dd) * SEQ + ns0 + chunk * 8) = val;
        }
    }
}

// ---------------- Flash attention v13: SPLIT-K (2 splits of 1024 keys) ----------------
// v12 body; grid 1024 -> 4 blocks/CU (4 waves/SIMD). Writes unnormalized f32
// partial O + per-row (m,l) stats (log2 domain); merge kernel combines.
__global__ __launch_bounds__(256, 4) void attn_split_kernel(
    const bf16_t* __restrict__ Q, const bf16_t* __restrict__ K,
    const bf16_t* __restrict__ Vt,
    float* __restrict__ OP, float* __restrict__ MS, float* __restrict__ LS)
{
    __shared__ bf16_t Ks[2][64][64];
    __shared__ bf16_t Vs[2][64][64];
    const int tid = threadIdx.x;
    const int wave = tid >> 6, lane = tid & 63;
    const int lhi = lane >> 4, llo = lane & 15;
    // XCD swizzle: 1024 blocks, 128/XCD -> 4 complete bh per XCD
    const int o = blockIdx.x;
    const int w = (o & 7) * 128 + (o >> 3);
    const int split = w & 1, qt = (w >> 1) & 15, bh = w >> 5;
    const bf16_t* Qb = Q + (size_t)bh * SEQ * HDIM;
    const bf16_t* Kb = K + (size_t)bh * SEQ * HDIM;
    const bf16_t* Vb = Vt + (size_t)bh * HDIM * SEQ;
    const int q0 = qt * 128 + wave * 32;
    const size_t KOFF = (size_t)split * 1024;      // key offset of this split
    const int NTL = 16;                            // local tiles

    const int ksr = tid >> 3, kg = tid & 7;
    const int kcol = (kg * 8) ^ ((ksr & 7) * 8);
    const int vd = tid >> 3, vg = tid & 7;
    const int pkA = (32*(vg>>2) + 8*((2*vg)&3)   + 4*((vg>>1)&1)) ^ ((vd & 7) * 8);
    const int pkB = (32*(vg>>2) + 8*((2*vg+1)&3) + 4*((vg>>1)&1)) ^ ((vd & 7) * 8);

    bf16x8 aq[2][2];
    #pragma unroll
    for (int qb = 0; qb < 2; ++qb)
        #pragma unroll
        for (int ks = 0; ks < 2; ++ks)
            aq[qb][ks] = *reinterpret_cast<const bf16x8*>(
                Qb + (size_t)(q0 + qb*16 + llo) * HDIM + ks*32 + lhi*8);

    bf16x8 ones;
    #pragma unroll
    for (int e = 0; e < 8; ++e) ones[e] = (bf16_t)1.0f;

    f32x4 acc_o[2][4] = {};
    f32x4 acc_l[2] = {};
    float mstat[2];
    const float THR = 8.0f * LOG2E;

    uint4 kreg0, kreg1, vreg0, vreg1;
    bf16x8 apA[2][2], apB[2][2];
    bf16x8 bvA[2][4], bvB[2][4];

    auto vmax4 = [](const f32x4& v) {
        return fmaxf(fmaxf(v[0], v[1]), fmaxf(v[2], v[3]));
    };

    kreg0 = *reinterpret_cast<const uint4*>(Kb + (KOFF + ksr) * HDIM + kg*8);
    kreg1 = *reinterpret_cast<const uint4*>(Kb + (KOFF + ksr + 32) * HDIM + kg*8);
    vreg0 = *reinterpret_cast<const uint4*>(Vb + (size_t)vd * SEQ + KOFF + vg*8);
    vreg1 = *reinterpret_cast<const uint4*>(Vb + (size_t)(vd + 32) * SEQ + KOFF + vg*8);
    *reinterpret_cast<uint4*>(&Ks[0][ksr][kcol]) = kreg0;
    *reinterpret_cast<uint4*>(&Ks[0][ksr + 32][kcol]) = kreg1;
    *reinterpret_cast<uint2*>(&Vs[0][vd][pkA]) = make_uint2(vreg0.x, vreg0.y);
    *reinterpret_cast<uint2*>(&Vs[0][vd][pkB]) = make_uint2(vreg0.z, vreg0.w);
    *reinterpret_cast<uint2*>(&Vs[0][vd + 32][pkA]) = make_uint2(vreg1.x, vreg1.y);
    *reinterpret_cast<uint2*>(&Vs[0][vd + 32][pkB]) = make_uint2(vreg1.z, vreg1.w);
    __syncthreads();

    kreg0 = *reinterpret_cast<const uint4*>(Kb + (KOFF + 64 + ksr) * HDIM + kg*8);
    kreg1 = *reinterpret_cast<const uint4*>(Kb + (KOFF + 64 + ksr + 32) * HDIM + kg*8);
    vreg0 = *reinterpret_cast<const uint4*>(Vb + (size_t)vd * SEQ + KOFF + 64 + vg*8);
    vreg1 = *reinterpret_cast<const uint4*>(Vb + (size_t)(vd + 32) * SEQ + KOFF + 64 + vg*8);

    {   // local tile 0
        f32x4 s[2][4] = {};
        __builtin_amdgcn_s_setprio(1);
        #pragma unroll
        for (int kb = 0; kb < 4; ++kb)
            #pragma unroll
            for (int ks = 0; ks < 2; ++ks) {
                bf16x8 kf = *reinterpret_cast<const bf16x8*>(
                    &Ks[0][kb*16 + llo][(ks*32 + lhi*8) ^ ((llo & 7) * 8)]);
                #pragma unroll
                for (int qb = 0; qb < 2; ++qb)
                    s[qb][kb] = __builtin_amdgcn_mfma_f32_16x16x32_bf16(kf, aq[qb][ks], s[qb][kb], 0, 0, 0);
            }
        __builtin_amdgcn_s_setprio(0);
        #pragma unroll
        for (int qb = 0; qb < 2; ++qb) {
            float mx = fmaxf(fmaxf(vmax4(s[qb][0]), vmax4(s[qb][1])),
                             fmaxf(vmax4(s[qb][2]), vmax4(s[qb][3])));
            mx = fmaxf(mx, __shfl_xor(mx, 16, 64));
            mx = fmaxf(mx, __shfl_xor(mx, 32, 64));
            mstat[qb] = mx;
            #pragma unroll
            for (int kp = 0; kp < 2; ++kp)
                #pragma unroll
                for (int j = 0; j < 4; ++j) {
                    apA[qb][kp][j]     = (bf16_t)__builtin_amdgcn_exp2f(s[qb][2*kp][j]     - mx);
                    apA[qb][kp][4 + j] = (bf16_t)__builtin_amdgcn_exp2f(s[qb][2*kp + 1][j] - mx);
                }
        }
        #pragma unroll
        for (int kp = 0; kp < 2; ++kp)
            #pragma unroll
            for (int qb = 0; qb < 2; ++qb)
                acc_l[qb] = __builtin_amdgcn_mfma_f32_16x16x32_bf16(apA[qb][kp], ones, acc_l[qb], 0, 0, 0);
        #pragma unroll
        for (int kp = 0; kp < 2; ++kp)
            #pragma unroll
            for (int db = 0; db < 4; ++db)
                bvA[kp][db] = *reinterpret_cast<const bf16x8*>(
                    &Vs[0][db*16 + llo][(kp*32 + lhi*8) ^ ((llo & 7) * 8)]);
        *reinterpret_cast<uint4*>(&Ks[1][ksr][kcol]) = kreg0;
        *reinterpret_cast<uint4*>(&Ks[1][ksr + 32][kcol]) = kreg1;
        *reinterpret_cast<uint2*>(&Vs[1][vd][pkA]) = make_uint2(vreg0.x, vreg0.y);
        *reinterpret_cast<uint2*>(&Vs[1][vd][pkB]) = make_uint2(vreg0.z, vreg0.w);
        *reinterpret_cast<uint2*>(&Vs[1][vd + 32][pkA]) = make_uint2(vreg1.x, vreg1.y);
        *reinterpret_cast<uint2*>(&Vs[1][vd + 32][pkB]) = make_uint2(vreg1.z, vreg1.w);
        __syncthreads();
    }

    auto body = [&](int lt, bf16x8 (&apIn)[2][2], bf16x8 (&bvIn)[2][4],
                    bf16x8 (&apOut)[2][2], bf16x8 (&bvOut)[2][4]) {
        const int cur = lt & 1, nxt = cur ^ 1;
        if (lt + 1 < NTL) {
            const size_t koff = KOFF + (size_t)(lt + 1) * 64;
            kreg0 = *reinterpret_cast<const uint4*>(Kb + (koff + ksr) * HDIM + kg*8);
            kreg1 = *reinterpret_cast<const uint4*>(Kb + (koff + ksr + 32) * HDIM + kg*8);
            vreg0 = *reinterpret_cast<const uint4*>(Vb + (size_t)vd * SEQ + koff + vg*8);
            vreg1 = *reinterpret_cast<const uint4*>(Vb + (size_t)(vd + 32) * SEQ + koff + vg*8);
        }
        f32x4 s[2][4] = {};
        __builtin_amdgcn_s_setprio(1);
        #pragma unroll
        for (int kb = 0; kb < 4; ++kb)
            #pragma unroll
            for (int ks = 0; ks < 2; ++ks) {
                bf16x8 kf = *reinterpret_cast<const bf16x8*>(
                    &Ks[cur][kb*16 + llo][(ks*32 + lhi*8) ^ ((llo & 7) * 8)]);
                #pragma unroll
                for (int qb = 0; qb < 2; ++qb)
                    s[qb][kb] = __builtin_amdgcn_mfma_f32_16x16x32_bf16(kf, aq[qb][ks], s[qb][kb], 0, 0, 0);
            }
        __builtin_amdgcn_s_setprio(0);

        float lmax[2];
        bool ok = true;
        #pragma unroll
        for (int qb = 0; qb < 2; ++qb) {
            float mx = fmaxf(fmaxf(vmax4(s[qb][0]), vmax4(s[qb][1])),
                             fmaxf(vmax4(s[qb][2]), vmax4(s[qb][3])));
            lmax[qb] = mx;
            ok &= (mx <= mstat[qb] + THR);
        }
        if (!__all(ok)) {
            #pragma unroll
            for (int kp = 0; kp < 2; ++kp)
                #pragma unroll
                for (int db = 0; db < 4; ++db)
                    #pragma unroll
                    for (int qb = 0; qb < 2; ++qb)
                        acc_o[qb][db] = __builtin_amdgcn_mfma_f32_16x16x32_bf16(apIn[qb][kp], bvIn[kp][db], acc_o[qb][db], 0, 0, 0);
            #pragma unroll
            for (int kp = 0; kp < 2; ++kp)
                #pragma unroll
                for (int db = 0; db < 4; ++db)
                    #pragma unroll
                    for (int e = 0; e < 8; ++e) bvIn[kp][db][e] = (bf16_t)0.f;
            #pragma unroll
            for (int qb = 0; qb < 2; ++qb) {
                float mx = lmax[qb];
                mx = fmaxf(mx, __shfl_xor(mx, 16, 64));
                mx = fmaxf(mx, __shfl_xor(mx, 32, 64));
                float mold = mstat[qb];
                float mn = fmaxf(mold, mx);
                float alpha = __builtin_amdgcn_exp2f(mold - mn);
                mstat[qb] = mn;
                #pragma unroll
                for (int r = 0; r < 4; ++r) {
                    float av = __shfl(alpha, (lane & 48) >> 2 | r, 64);
                    acc_l[qb][r] *= av;
                    #pragma unroll
                    for (int db = 0; db < 4; ++db) acc_o[qb][db][r] *= av;
                }
            }
        }

        __builtin_amdgcn_s_setprio(1);
        #pragma unroll
        for (int kp = 0; kp < 2; ++kp) {
            #pragma unroll
            for (int qb = 0; qb < 2; ++qb)
                #pragma unroll
                for (int j = 0; j < 4; ++j) {
                    apOut[qb][kp][j]     = (bf16_t)__builtin_amdgcn_exp2f(s[qb][2*kp][j]     - mstat[qb]);
                    apOut[qb][kp][4 + j] = (bf16_t)__builtin_amdgcn_exp2f(s[qb][2*kp + 1][j] - mstat[qb]);
                }
            #pragma unroll
            for (int db = 0; db < 4; ++db)
                #pragma unroll
                for (int qb = 0; qb < 2; ++qb)
                    acc_o[qb][db] = __builtin_amdgcn_mfma_f32_16x16x32_bf16(apIn[qb][kp], bvIn[kp][db], acc_o[qb][db], 0, 0, 0);
            #pragma unroll
            for (int qb = 0; qb < 2; ++qb)
                acc_l[qb] = __builtin_amdgcn_mfma_f32_16x16x32_bf16(apOut[qb][kp], ones, acc_l[qb], 0, 0, 0);
        }
        __builtin_amdgcn_s_setprio(0);

        #pragma unroll
        for (int kp = 0; kp < 2; ++kp)
            #pragma unroll
            for (int db = 0; db < 4; ++db)
                bvOut[kp][db] = *reinterpret_cast<const bf16x8*>(
                    &Vs[cur][db*16 + llo][(kp*32 + lhi*8) ^ ((llo & 7) * 8)]);

        if (lt + 1 < NTL) {
            *reinterpret_cast<uint4*>(&Ks[nxt][ksr][kcol]) = kreg0;
            *reinterpret_cast<uint4*>(&Ks[nxt][ksr + 32][kcol]) = kreg1;
            *reinterpret_cast<uint2*>(&Vs[nxt][vd][pkA]) = make_uint2(vreg0.x, vreg0.y);
            *reinterpret_cast<uint2*>(&Vs[nxt][vd][pkB]) = make_uint2(vreg0.z, vreg0.w);
            *reinterpret_cast<uint2*>(&Vs[nxt][vd + 32][pkA]) = make_uint2(vreg1.x, vreg1.y);
            *reinterpret_cast<uint2*>(&Vs[nxt][vd + 32][pkB]) = make_uint2(vreg1.z, vreg1.w);
        }
        __syncthreads();
    };

    for (int tp = 1; tp + 1 < NTL; tp += 2) {
        body(tp,     apA, bvA, apB, bvB);
        body(tp + 1, apB, bvB, apA, bvA);
    }
    body(NTL - 1, apA, bvA, apB, bvB);

    #pragma unroll
    for (int kp = 0; kp < 2; ++kp)
        #pragma unroll
        for (int db = 0; db < 4; ++db)
            #pragma unroll
            for (int qb = 0; qb < 2; ++qb)
                acc_o[qb][db] = __builtin_amdgcn_mfma_f32_16x16x32_bf16(apB[qb][kp], bvB[kp][db], acc_o[qb][db], 0, 0, 0);

    // write unnormalized partials (f32) + stats (log2 domain)
    float* op = OP + (((size_t)split * 32 + bh) * SEQ) * HDIM;
    #pragma unroll
    for (int qb = 0; qb < 2; ++qb) {
        #pragma unroll
        for (int r = 0; r < 4; ++r) {
            int q = q0 + qb*16 + lhi*4 + r;
            #pragma unroll
            for (int db = 0; db < 4; ++db)
                op[(size_t)q * HDIM + db*16 + llo] = acc_o[qb][db][r];
        }
        if (lhi == 0)
            MS[((size_t)split * 32 + bh) * SEQ + q0 + qb*16 + llo] = mstat[qb];
        if (llo == 0)
            #pragma unroll
            for (int r = 0; r < 4; ++r)
                LS[((size_t)split * 32 + bh) * SEQ + q0 + qb*16 + lhi*4 + r] = acc_l[qb][r];
    }
}

// ---------------- split-K merge: O = (w0*O0 + w1*O1) / (w0*l0 + w1*l1) ----------------
__global__ __launch_bounds__(256) void merge_kernel(
    const float* __restrict__ OP, const float* __restrict__ MS,
    const float* __restrict__ LS, bf16_t* __restrict__ O)
{
    const int t = blockIdx.x * 256 + threadIdx.x;   // 1,048,576 threads
    const int dq = t & 15, q = (t >> 4) & 2047, bh = t >> 15;
    const size_t r0 = (size_t)bh * SEQ + q;
    const size_t r1 = (size_t)(32 + bh) * SEQ + q;
    float m0 = MS[r0], m1 = MS[r1];
    float l0 = LS[r0], l1 = LS[r1];
    float M = fmaxf(m0, m1);
    float w0 = __builtin_amdgcn_exp2f(m0 - M);
    float w1 = __builtin_amdgcn_exp2f(m1 - M);
    float inv = 1.0f / (w0 * l0 + w1 * l1);
    float4 o0 = *reinterpret_cast<const float4*>(OP + r0 * HDIM + dq * 4);
    float4 o1 = *reinterpret_cast<const float4*>(OP + r1 * HDIM + dq * 4);
    bf16x4 res;
    res[0] = (bf16_t)((o0.x * w0 + o1.x * w1) * inv);
    res[1] = (bf16_t)((o0.y * w0 + o1.y * w1) * inv);
    res[2] = (bf16_t)((o0.z * w0 + o1.z * w1) * inv);
    res[3] = (bf16_t)((o0.w * w0 + o1.w * w1) * inv);
    const int b = bh >> 3, h = bh & 7;
    *reinterpret_cast<bf16x4*>(O + ((size_t)(b * SEQ + q) * DIM + h * HDIM + dq * 4)) = res;
}

// ---------------- Output proj GEMM (R15-identical) ----------------
__global__ __launch_bounds__(256) void gemm_proj_kernel(
    const bf16_t* __restrict__ X, const bf16_t* __restrict__ W,
    const float* __restrict__ bias, float* __restrict__ out)
{
    __shared__ bf16_t As[128][64];
    __shared__ bf16_t Bs[64][64];
    const int tid = threadIdx.x;
    const int wave = tid >> 6, lane = tid & 63;
    const int lhi = lane >> 4, llo = lane & 15;
    const int o = blockIdx.x;
    const int x = o & 7, i0 = o >> 3;
    const int m0 = (x * 8 + (i0 & 7)) * 128;
    const int n0 = (i0 >> 3) * 64;
    const int wr = (wave >> 1) * 64, wc = (wave & 1) * 32;
    f32x4 acc[4][2] = {};

    const int srow = wave * 32 + (lane >> 3);
    const int srowB = wave * 16 + (lane >> 3);
    const int scol = (lane & 7) * 8;
    const bf16_t* gA = X + (size_t)(m0 + srow) * DIM + scol;
    const bf16_t* gB = W + (size_t)(n0 + srowB) * DIM + scol;

    for (int k0 = 0; k0 < DIM; k0 += 64) {
        #pragma unroll
        for (int p = 0; p < 4; ++p)
            ASYNC_COPY16(gA + (size_t)p * 8 * DIM + k0, &As[wave*32 + p*8][0]);
        #pragma unroll
        for (int p = 0; p < 2; ++p)
            ASYNC_COPY16(gB + (size_t)p * 8 * DIM + k0, &Bs[wave*16 + p*8][0]);
        __syncthreads();
        #pragma unroll
        for (int ks = 0; ks < 2; ++ks) {
            bf16x8 af[4], bfr[2];
            #pragma unroll
            for (int i = 0; i < 4; ++i)
                af[i] = *reinterpret_cast<const bf16x8*>(&As[wr + i*16 + llo][ks*32 + lhi*8]);
            #pragma unroll
            for (int j = 0; j < 2; ++j)
                bfr[j] = *reinterpret_cast<const bf16x8*>(&Bs[wc + j*16 + llo][ks*32 + lhi*8]);
            __builtin_amdgcn_s_setprio(1);
            #pragma unroll
            for (int i = 0; i < 4; ++i)
                #pragma unroll
                for (int j = 0; j < 2; ++j)
                    acc[i][j] = __builtin_amdgcn_mfma_f32_16x16x32_bf16(af[i], bfr[j], acc[i][j], 0, 0, 0);
            __builtin_amdgcn_s_setprio(0);
        }
        __syncthreads();
    }

    #pragma unroll
    for (int j = 0; j < 2; ++j) {
        int col = n0 + wc + j*16 + llo;
        float bv = bias[col];
        #pragma unroll
        for (int i = 0; i < 4; ++i)
            #pragma unroll
            for (int r = 0; r < 4; ++r) {
                int m = m0 + wr + i*16 + lhi*4 + r;
                out[(size_t)m * DIM + col] = acc[i][j][r] + bv;
            }
    }
}

extern "C" void kernel_launch(void* const* d_in, const int* in_sizes, int n_in,
                              void* d_out, int out_size, void* d_ws, size_t ws_size,
                              hipStream_t stream) {
    const float* x      = (const float*)d_in[0];
    const float* w_qkv  = (const float*)d_in[1];
    const float* b_qkv  = (const float*)d_in[2];
    const float* w_proj = (const float*)d_in[3];
    const float* b_proj = (const float*)d_in[4];
    float* out = (float*)d_out;

    const size_t NX  = (size_t)MTOT * DIM;
    const size_t NWQ = (size_t)3 * DIM * DIM;
    const size_t NWP = (size_t)DIM * DIM;
    const size_t NQ  = (size_t)BATCH * NHEAD * SEQ * HDIM;   // 4,194,304

    bf16_t* Xb    = (bf16_t*)d_ws;
    bf16_t* Wqkv  = Xb + NX;
    bf16_t* Wproj = Wqkv + NWQ;
    bf16_t* Qb    = Wproj + NWP;
    bf16_t* Kb    = Qb + NQ;
    bf16_t* Vtb   = Kb + NQ;
    bf16_t* AOb   = Vtb + NQ;
    float*  OP    = (float*)(AOb + NQ);          // [2][32][2048][64] f32
    float*  MS    = OP + 2 * NQ;                  // [2][32][2048]
    float*  LS    = MS + 2 * 32 * SEQ;            // [2][32][2048]

    cvt_kernel<<<(int)((NX + NWQ + NWP) / 1024), 256, 0, stream>>>(x, w_qkv, w_proj, Xb);

    gemm_qkv_kernel<<<768, 256, 0, stream>>>(Xb, Wqkv, b_qkv, Qb, Kb, Vtb);

    attn_split_kernel<<<1024, 256, 0, stream>>>(Qb, Kb, Vtb, OP, MS, LS);

    merge_kernel<<<4096, 256, 0, stream>>>(OP, MS, LS, AOb);

    gemm_proj_kernel<<<512, 256, 0, stream>>>(AOb, Wproj, b_proj, out);
}

// Round 17
// 100.449 us; speedup vs baseline: 3.2261x; 3.2261x over previous
//
#include <hip/hip_runtime.h>

#define DIM 512
#define NHEAD 8
#define HDIM 64
#define BATCH 4
#define SEQ 2048
#define MTOT (BATCH*SEQ)
#define SCALE 0.125f
#define LOG2E 1.4426950408889634f

typedef __bf16 bf16_t;
typedef __bf16 bf16x8 __attribute__((ext_vector_type(8)));
typedef __bf16 bf16x4 __attribute__((ext_vector_type(4)));
typedef __bf16 bf16x2 __attribute__((ext_vector_type(2)));
typedef float f32x4 __attribute__((ext_vector_type(4)));

#define ASYNC_COPY16(g, l) __builtin_amdgcn_global_load_lds( \
    (const __attribute__((address_space(1))) void*)(g),      \
    (__attribute__((address_space(3))) void*)(l), 16, 0, 0)

// ---------------- fused fp32 -> bf16 convert (x | w_qkv | w_proj) ----------------
#define NX_ELEM  (4194304)
#define NWQ_ELEM (786432)
#define NWP_ELEM (262144)
__global__ __launch_bounds__(256) void cvt_kernel(const float* __restrict__ x,
                                                  const float* __restrict__ wq,
                                                  const float* __restrict__ wp,
                                                  bf16_t* __restrict__ out) {
    int i = (blockIdx.x * 256 + threadIdx.x) * 4;
    const float* src;
    if (i < NX_ELEM)                 src = x  + i;
    else if (i < NX_ELEM + NWQ_ELEM) src = wq + (i - NX_ELEM);
    else                             src = wp + (i - NX_ELEM - NWQ_ELEM);
    float4 v = *reinterpret_cast<const float4*>(src);
    bf16x4 o;
    o[0] = (bf16_t)v.x; o[1] = (bf16_t)v.y; o[2] = (bf16_t)v.z; o[3] = (bf16_t)v.w;
    *reinterpret_cast<bf16x4*>(out + i) = o;
}

// ---------------- QKV GEMM (R15-identical) ----------------
__global__ __launch_bounds__(256) void gemm_qkv_kernel(
    const bf16_t* __restrict__ X, const bf16_t* __restrict__ W,
    const float* __restrict__ bias,
    bf16_t* __restrict__ Qo, bf16_t* __restrict__ Ko, bf16_t* __restrict__ Vto)
{
    __shared__ bf16_t smem[16384];
    bf16_t (*As)[64] = reinterpret_cast<bf16_t (*)[64]>(smem);
    bf16_t (*Bs)[64] = reinterpret_cast<bf16_t (*)[64]>(smem + 8192);
    unsigned int* Lw = reinterpret_cast<unsigned int*>(smem);
    const int tid = threadIdx.x;
    const int wave = tid >> 6, lane = tid & 63;
    const int lhi = lane >> 4, llo = lane & 15;
    const int o = blockIdx.x;
    const int x = o & 7, i0 = o >> 3;
    const int m0 = (x * 8 + (i0 & 7)) * 128;
    const int n0 = (i0 >> 3) * 128;
    const int wr = (wave >> 1) * 64, wc = (wave & 1) * 64;
    f32x4 acc[4][4] = {};

    const int srow = wave * 32 + (lane >> 3);
    const int scol = (lane & 7) * 8;
    const bf16_t* gA = X + (size_t)(m0 + srow) * DIM + scol;
    const bf16_t* gB = W + (size_t)(n0 + srow) * DIM + scol;

    for (int k0 = 0; k0 < DIM; k0 += 64) {
        #pragma unroll
        for (int p = 0; p < 4; ++p) {
            ASYNC_COPY16(gA + (size_t)p * 8 * DIM + k0, &As[wave*32 + p*8][0]);
            ASYNC_COPY16(gB + (size_t)p * 8 * DIM + k0, &Bs[wave*32 + p*8][0]);
        }
        __syncthreads();
        #pragma unroll
        for (int ks = 0; ks < 2; ++ks) {
            bf16x8 af[4], bfr[4];
            #pragma unroll
            for (int i = 0; i < 4; ++i)
                af[i] = *reinterpret_cast<const bf16x8*>(&As[wr + i*16 + llo][ks*32 + lhi*8]);
            #pragma unroll
            for (int j = 0; j < 4; ++j)
                bfr[j] = *reinterpret_cast<const bf16x8*>(&Bs[wc + j*16 + llo][ks*32 + lhi*8]);
            __builtin_amdgcn_s_setprio(1);
            #pragma unroll
            for (int i = 0; i < 4; ++i)
                #pragma unroll
                for (int j = 0; j < 4; ++j)
                    acc[i][j] = __builtin_amdgcn_mfma_f32_16x16x32_bf16(af[i], bfr[j], acc[i][j], 0, 0, 0);
            __builtin_amdgcn_s_setprio(0);
        }
        __syncthreads();
    }

    const int b = m0 >> 11, ns0 = m0 & 2047;

    if (n0 < 1024) {
        const float qscale = (n0 < 512) ? (SCALE * LOG2E) : 1.0f;
        bf16_t* __restrict__ dst = (n0 < 512) ? Qo : Ko;
        #pragma unroll
        for (int j = 0; j < 4; ++j) {
            int ddc = wc + j*16 + llo;
            float bv = bias[n0 + ddc];
            #pragma unroll
            for (int i = 0; i < 4; ++i)
                #pragma unroll
                for (int r = 0; r < 4; ++r) {
                    int ml = wr + i*16 + lhi*4 + r;
                    smem[ml * 128 + (ddc ^ (((ml >> 2) & 3) * 16))] =
                        (bf16_t)((acc[i][j][r] + bv) * qscale);
                }
        }
        __syncthreads();
        #pragma unroll
        for (int k = 0; k < 8; ++k) {
            int c = tid + k * 256;
            int row = c >> 4, colc = (c & 15) * 8;
            uint4 val = *reinterpret_cast<const uint4*>(
                &smem[row * 128 + (colc ^ (((row >> 2) & 3) * 16))]);
            int col = n0 + colc;
            int hh = (col >> 6) & 7, dd = col & 63;
            size_t bh = (size_t)(b * NHEAD + hh);
            *reinterpret_cast<uint4*>(dst + (bh * SEQ + ns0 + row) * HDIM + dd) = val;
        }
    } else {
        #pragma unroll
        for (int j = 0; j < 4; ++j) {
            int ddc = wc + j*16 + llo;
            float bv = bias[n0 + ddc];
            int xsw = (ddc & 7) * 4;
            #pragma unroll
            for (int i = 0; i < 4; ++i) {
                int dwb = (wr >> 1) + i*8 + lhi*2;
                #pragma unroll
                for (int r2 = 0; r2 < 2; ++r2) {
                    bf16x2 t;
                    t[0] = (bf16_t)(acc[i][j][2*r2]     + bv);
                    t[1] = (bf16_t)(acc[i][j][2*r2 + 1] + bv);
                    Lw[ddc * 64 + ((dwb + r2) ^ xsw)] = __builtin_bit_cast(unsigned int, t);
                }
            }
        }
        __syncthreads();
        const int hh_base = (n0 - 1024) >> 6;
        const int chunk = tid & 15;
        #pragma unroll
        for (int rd = 0; rd < 8; ++rd) {
            int ddc = rd * 16 + (tid >> 4);
            uint4 val = *reinterpret_cast<const uint4*>(
                &Lw[ddc * 64 + ((chunk * 4) ^ ((ddc & 7) * 4))]);
            int dd = ddc & 63;
            int hh = hh_base + (ddc >> 6);
            size_t bh = (size_t)(b * NHEAD + hh);
            *reinterpret_cast<uint4*>(Vto + (bh * HDIM + dd) * SEQ + ns0 + chunk * 8) = val;
        }
    }
}

// ---------------- Flash attention v13b: SPLIT-K, launch_bounds(256,2) ----------------
// (256,2) keeps compiler at ~104 VGPR (no spills); HW still co-schedules
// 4 blocks/CU since 104 VGPR <= 128 and 4x32KB LDS fits. grid 1024.
__global__ __launch_bounds__(256, 2) void attn_split_kernel(
    const bf16_t* __restrict__ Q, const bf16_t* __restrict__ K,
    const bf16_t* __restrict__ Vt,
    float* __restrict__ OP, float* __restrict__ MS, float* __restrict__ LS)
{
    __shared__ bf16_t Ks[2][64][64];
    __shared__ bf16_t Vs[2][64][64];
    const int tid = threadIdx.x;
    const int wave = tid >> 6, lane = tid & 63;
    const int lhi = lane >> 4, llo = lane & 15;
    const int o = blockIdx.x;
    const int w = (o & 7) * 128 + (o >> 3);
    const int split = w & 1, qt = (w >> 1) & 15, bh = w >> 5;
    const bf16_t* Qb = Q + (size_t)bh * SEQ * HDIM;
    const bf16_t* Kb = K + (size_t)bh * SEQ * HDIM;
    const bf16_t* Vb = Vt + (size_t)bh * HDIM * SEQ;
    const int q0 = qt * 128 + wave * 32;
    const size_t KOFF = (size_t)split * 1024;
    const int NTL = 16;

    const int ksr = tid >> 3, kg = tid & 7;
    const int kcol = (kg * 8) ^ ((ksr & 7) * 8);
    const int vd = tid >> 3, vg = tid & 7;
    const int pkA = (32*(vg>>2) + 8*((2*vg)&3)   + 4*((vg>>1)&1)) ^ ((vd & 7) * 8);
    const int pkB = (32*(vg>>2) + 8*((2*vg+1)&3) + 4*((vg>>1)&1)) ^ ((vd & 7) * 8);

    bf16x8 aq[2][2];
    #pragma unroll
    for (int qb = 0; qb < 2; ++qb)
        #pragma unroll
        for (int ks = 0; ks < 2; ++ks)
            aq[qb][ks] = *reinterpret_cast<const bf16x8*>(
                Qb + (size_t)(q0 + qb*16 + llo) * HDIM + ks*32 + lhi*8);

    bf16x8 ones;
    #pragma unroll
    for (int e = 0; e < 8; ++e) ones[e] = (bf16_t)1.0f;

    f32x4 acc_o[2][4] = {};
    f32x4 acc_l[2] = {};
    float mstat[2];
    const float THR = 8.0f * LOG2E;

    uint4 kreg0, kreg1, vreg0, vreg1;
    bf16x8 apA[2][2], apB[2][2];
    bf16x8 bvA[2][4], bvB[2][4];

    auto vmax4 = [](const f32x4& v) {
        return fmaxf(fmaxf(v[0], v[1]), fmaxf(v[2], v[3]));
    };

    kreg0 = *reinterpret_cast<const uint4*>(Kb + (KOFF + ksr) * HDIM + kg*8);
    kreg1 = *reinterpret_cast<const uint4*>(Kb + (KOFF + ksr + 32) * HDIM + kg*8);
    vreg0 = *reinterpret_cast<const uint4*>(Vb + (size_t)vd * SEQ + KOFF + vg*8);
    vreg1 = *reinterpret_cast<const uint4*>(Vb + (size_t)(vd + 32) * SEQ + KOFF + vg*8);
    *reinterpret_cast<uint4*>(&Ks[0][ksr][kcol]) = kreg0;
    *reinterpret_cast<uint4*>(&Ks[0][ksr + 32][kcol]) = kreg1;
    *reinterpret_cast<uint2*>(&Vs[0][vd][pkA]) = make_uint2(vreg0.x, vreg0.y);
    *reinterpret_cast<uint2*>(&Vs[0][vd][pkB]) = make_uint2(vreg0.z, vreg0.w);
    *reinterpret_cast<uint2*>(&Vs[0][vd + 32][pkA]) = make_uint2(vreg1.x, vreg1.y);
    *reinterpret_cast<uint2*>(&Vs[0][vd + 32][pkB]) = make_uint2(vreg1.z, vreg1.w);
    __syncthreads();

    kreg0 = *reinterpret_cast<const uint4*>(Kb + (KOFF + 64 + ksr) * HDIM + kg*8);
    kreg1 = *reinterpret_cast<const uint4*>(Kb + (KOFF + 64 + ksr + 32) * HDIM + kg*8);
    vreg0 = *reinterpret_cast<const uint4*>(Vb + (size_t)vd * SEQ + KOFF + 64 + vg*8);
    vreg1 = *reinterpret_cast<const uint4*>(Vb + (size_t)(vd + 32) * SEQ + KOFF + 64 + vg*8);

    {   // local tile 0
        f32x4 s[2][4] = {};
        __builtin_amdgcn_s_setprio(1);
        #pragma unroll
        for (int kb = 0; kb < 4; ++kb)
            #pragma unroll
            for (int ks = 0; ks < 2; ++ks) {
                bf16x8 kf = *reinterpret_cast<const bf16x8*>(
                    &Ks[0][kb*16 + llo][(ks*32 + lhi*8) ^ ((llo & 7) * 8)]);
                #pragma unroll
                for (int qb = 0; qb < 2; ++qb)
                    s[qb][kb] = __builtin_amdgcn_mfma_f32_16x16x32_bf16(kf, aq[qb][ks], s[qb][kb], 0, 0, 0);
            }
        __builtin_amdgcn_s_setprio(0);
        #pragma unroll
        for (int qb = 0; qb < 2; ++qb) {
            float mx = fmaxf(fmaxf(vmax4(s[qb][0]), vmax4(s[qb][1])),
                             fmaxf(vmax4(s[qb][2]), vmax4(s[qb][3])));
            mx = fmaxf(mx, __shfl_xor(mx, 16, 64));
            mx = fmaxf(mx, __shfl_xor(mx, 32, 64));
            mstat[qb] = mx;
            #pragma unroll
            for (int kp = 0; kp < 2; ++kp)
                #pragma unroll
                for (int j = 0; j < 4; ++j) {
                    apA[qb][kp][j]     = (bf16_t)__builtin_amdgcn_exp2f(s[qb][2*kp][j]     - mx);
                    apA[qb][kp][4 + j] = (bf16_t)__builtin_amdgcn_exp2f(s[qb][2*kp + 1][j] - mx);
                }
        }
        #pragma unroll
        for (int kp = 0; kp < 2; ++kp)
            #pragma unroll
            for (int qb = 0; qb < 2; ++qb)
                acc_l[qb] = __builtin_amdgcn_mfma_f32_16x16x32_bf16(apA[qb][kp], ones, acc_l[qb], 0, 0, 0);
        #pragma unroll
        for (int kp = 0; kp < 2; ++kp)
            #pragma unroll
            for (int db = 0; db < 4; ++db)
                bvA[kp][db] = *reinterpret_cast<const bf16x8*>(
                    &Vs[0][db*16 + llo][(kp*32 + lhi*8) ^ ((llo & 7) * 8)]);
        *reinterpret_cast<uint4*>(&Ks[1][ksr][kcol]) = kreg0;
        *reinterpret_cast<uint4*>(&Ks[1][ksr + 32][kcol]) = kreg1;
        *reinterpret_cast<uint2*>(&Vs[1][vd][pkA]) = make_uint2(vreg0.x, vreg0.y);
        *reinterpret_cast<uint2*>(&Vs[1][vd][pkB]) = make_uint2(vreg0.z, vreg0.w);
        *reinterpret_cast<uint2*>(&Vs[1][vd + 32][pkA]) = make_uint2(vreg1.x, vreg1.y);
        *reinterpret_cast<uint2*>(&Vs[1][vd + 32][pkB]) = make_uint2(vreg1.z, vreg1.w);
        __syncthreads();
    }

    auto body = [&](int lt, bf16x8 (&apIn)[2][2], bf16x8 (&bvIn)[2][4],
                    bf16x8 (&apOut)[2][2], bf16x8 (&bvOut)[2][4]) {
        const int cur = lt & 1, nxt = cur ^ 1;
        if (lt + 1 < NTL) {
            const size_t koff = KOFF + (size_t)(lt + 1) * 64;
            kreg0 = *reinterpret_cast<const uint4*>(Kb + (koff + ksr) * HDIM + kg*8);
            kreg1 = *reinterpret_cast<const uint4*>(Kb + (koff + ksr + 32) * HDIM + kg*8);
            vreg0 = *reinterpret_cast<const uint4*>(Vb + (size_t)vd * SEQ + koff + vg*8);
            vreg1 = *reinterpret_cast<const uint4*>(Vb + (size_t)(vd + 32) * SEQ + koff + vg*8);
        }
        f32x4 s[2][4] = {};
        __builtin_amdgcn_s_setprio(1);
        #pragma unroll
        for (int kb = 0; kb < 4; ++kb)
            #pragma unroll
            for (int ks = 0; ks < 2; ++ks) {
                bf16x8 kf = *reinterpret_cast<const bf16x8*>(
                    &Ks[cur][kb*16 + llo][(ks*32 + lhi*8) ^ ((llo & 7) * 8)]);
                #pragma unroll
                for (int qb = 0; qb < 2; ++qb)
                    s[qb][kb] = __builtin_amdgcn_mfma_f32_16x16x32_bf16(kf, aq[qb][ks], s[qb][kb], 0, 0, 0);
            }
        __builtin_amdgcn_s_setprio(0);

        float lmax[2];
        bool ok = true;
        #pragma unroll
        for (int qb = 0; qb < 2; ++qb) {
            float mx = fmaxf(fmaxf(vmax4(s[qb][0]), vmax4(s[qb][1])),
                             fmaxf(vmax4(s[qb][2]), vmax4(s[qb][3])));
            lmax[qb] = mx;
            ok &= (mx <= mstat[qb] + THR);
        }
        if (!__all(ok)) {
            #pragma unroll
            for (int kp = 0; kp < 2; ++kp)
                #pragma unroll
                for (int db = 0; db < 4; ++db)
                    #pragma unroll
                    for (int qb = 0; qb < 2; ++qb)
                        acc_o[qb][db] = __builtin_amdgcn_mfma_f32_16x16x32_bf16(apIn[qb][kp], bvIn[kp][db], acc_o[qb][db], 0, 0, 0);
            #pragma unroll
            for (int kp = 0; kp < 2; ++kp)
                #pragma unroll
                for (int db = 0; db < 4; ++db)
                    #pragma unroll
                    for (int e = 0; e < 8; ++e) bvIn[kp][db][e] = (bf16_t)0.f;
            #pragma unroll
            for (int qb = 0; qb < 2; ++qb) {
                float mx = lmax[qb];
                mx = fmaxf(mx, __shfl_xor(mx, 16, 64));
                mx = fmaxf(mx, __shfl_xor(mx, 32, 64));
                float mold = mstat[qb];
                float mn = fmaxf(mold, mx);
                float alpha = __builtin_amdgcn_exp2f(mold - mn);
                mstat[qb] = mn;
                #pragma unroll
                for (int r = 0; r < 4; ++r) {
                    float av = __shfl(alpha, (lane & 48) >> 2 | r, 64);
                    acc_l[qb][r] *= av;
                    #pragma unroll
                    for (int db = 0; db < 4; ++db) acc_o[qb][db][r] *= av;
                }
            }
        }

        __builtin_amdgcn_s_setprio(1);
        #pragma unroll
        for (int kp = 0; kp < 2; ++kp) {
            #pragma unroll
            for (int qb = 0; qb < 2; ++qb)
                #pragma unroll
                for (int j = 0; j < 4; ++j) {
                    apOut[qb][kp][j]     = (bf16_t)__builtin_amdgcn_exp2f(s[qb][2*kp][j]     - mstat[qb]);
                    apOut[qb][kp][4 + j] = (bf16_t)__builtin_amdgcn_exp2f(s[qb][2*kp + 1][j] - mstat[qb]);
                }
            #pragma unroll
            for (int db = 0; db < 4; ++db)
                #pragma unroll
                for (int qb = 0; qb < 2; ++qb)
                    acc_o[qb][db] = __builtin_amdgcn_mfma_f32_16x16x32_bf16(apIn[qb][kp], bvIn[kp][db], acc_o[qb][db], 0, 0, 0);
            #pragma unroll
            for (int qb = 0; qb < 2; ++qb)
                acc_l[qb] = __builtin_amdgcn_mfma_f32_16x16x32_bf16(apOut[qb][kp], ones, acc_l[qb], 0, 0, 0);
        }
        __builtin_amdgcn_s_setprio(0);

        #pragma unroll
        for (int kp = 0; kp < 2; ++kp)
            #pragma unroll
            for (int db = 0; db < 4; ++db)
                bvOut[kp][db] = *reinterpret_cast<const bf16x8*>(
                    &Vs[cur][db*16 + llo][(kp*32 + lhi*8) ^ ((llo & 7) * 8)]);

        if (lt + 1 < NTL) {
            *reinterpret_cast<uint4*>(&Ks[nxt][ksr][kcol]) = kreg0;
            *reinterpret_cast<uint4*>(&Ks[nxt][ksr + 32][kcol]) = kreg1;
            *reinterpret_cast<uint2*>(&Vs[nxt][vd][pkA]) = make_uint2(vreg0.x, vreg0.y);
            *reinterpret_cast<uint2*>(&Vs[nxt][vd][pkB]) = make_uint2(vreg0.z, vreg0.w);
            *reinterpret_cast<uint2*>(&Vs[nxt][vd + 32][pkA]) = make_uint2(vreg1.x, vreg1.y);
            *reinterpret_cast<uint2*>(&Vs[nxt][vd + 32][pkB]) = make_uint2(vreg1.z, vreg1.w);
        }
        __syncthreads();
    };

    for (int tp = 1; tp + 1 < NTL; tp += 2) {
        body(tp,     apA, bvA, apB, bvB);
        body(tp + 1, apB, bvB, apA, bvA);
    }
    body(NTL - 1, apA, bvA, apB, bvB);

    #pragma unroll
    for (int kp = 0; kp < 2; ++kp)
        #pragma unroll
        for (int db = 0; db < 4; ++db)
            #pragma unroll
            for (int qb = 0; qb < 2; ++qb)
                acc_o[qb][db] = __builtin_amdgcn_mfma_f32_16x16x32_bf16(apB[qb][kp], bvB[kp][db], acc_o[qb][db], 0, 0, 0);

    // write unnormalized partials (f32) + stats (log2 domain)
    float* op = OP + (((size_t)split * 32 + bh) * SEQ) * HDIM;
    #pragma unroll
    for (int qb = 0; qb < 2; ++qb) {
        #pragma unroll
        for (int r = 0; r < 4; ++r) {
            int q = q0 + qb*16 + lhi*4 + r;
            #pragma unroll
            for (int db = 0; db < 4; ++db)
                op[(size_t)q * HDIM + db*16 + llo] = acc_o[qb][db][r];
        }
        if (lhi == 0)
            MS[((size_t)split * 32 + bh) * SEQ + q0 + qb*16 + llo] = mstat[qb];
        if (llo == 0)
            #pragma unroll
            for (int r = 0; r < 4; ++r)
                LS[((size_t)split * 32 + bh) * SEQ + q0 + qb*16 + lhi*4 + r] = acc_l[qb][r];
    }
}

// ---------------- split-K merge ----------------
__global__ __launch_bounds__(256) void merge_kernel(
    const float* __restrict__ OP, const float* __restrict__ MS,
    const float* __restrict__ LS, bf16_t* __restrict__ O)
{
    const int t = blockIdx.x * 256 + threadIdx.x;
    const int dq = t & 15, q = (t >> 4) & 2047, bh = t >> 15;
    const size_t r0 = (size_t)bh * SEQ + q;
    const size_t r1 = (size_t)(32 + bh) * SEQ + q;
    float m0 = MS[r0], m1 = MS[r1];
    float l0 = LS[r0], l1 = LS[r1];
    float M = fmaxf(m0, m1);
    float w0 = __builtin_amdgcn_exp2f(m0 - M);
    float w1 = __builtin_amdgcn_exp2f(m1 - M);
    float inv = 1.0f / (w0 * l0 + w1 * l1);
    float4 o0 = *reinterpret_cast<const float4*>(OP + r0 * HDIM + dq * 4);
    float4 o1 = *reinterpret_cast<const float4*>(OP + r1 * HDIM + dq * 4);
    bf16x4 res;
    res[0] = (bf16_t)((o0.x * w0 + o1.x * w1) * inv);
    res[1] = (bf16_t)((o0.y * w0 + o1.y * w1) * inv);
    res[2] = (bf16_t)((o0.z * w0 + o1.z * w1) * inv);
    res[3] = (bf16_t)((o0.w * w0 + o1.w * w1) * inv);
    const int b = bh >> 3, h = bh & 7;
    *reinterpret_cast<bf16x4*>(O + ((size_t)(b * SEQ + q) * DIM + h * HDIM + dq * 4)) = res;
}

// ---------------- Output proj GEMM (R15-identical) ----------------
__global__ __launch_bounds__(256) void gemm_proj_kernel(
    const bf16_t* __restrict__ X, const bf16_t* __restrict__ W,
    const float* __restrict__ bias, float* __restrict__ out)
{
    __shared__ bf16_t As[128][64];
    __shared__ bf16_t Bs[64][64];
    const int tid = threadIdx.x;
    const int wave = tid >> 6, lane = tid & 63;
    const int lhi = lane >> 4, llo = lane & 15;
    const int o = blockIdx.x;
    const int x = o & 7, i0 = o >> 3;
    const int m0 = (x * 8 + (i0 & 7)) * 128;
    const int n0 = (i0 >> 3) * 64;
    const int wr = (wave >> 1) * 64, wc = (wave & 1) * 32;
    f32x4 acc[4][2] = {};

    const int srow = wave * 32 + (lane >> 3);
    const int srowB = wave * 16 + (lane >> 3);
    const int scol = (lane & 7) * 8;
    const bf16_t* gA = X + (size_t)(m0 + srow) * DIM + scol;
    const bf16_t* gB = W + (size_t)(n0 + srowB) * DIM + scol;

    for (int k0 = 0; k0 < DIM; k0 += 64) {
        #pragma unroll
        for (int p = 0; p < 4; ++p)
            ASYNC_COPY16(gA + (size_t)p * 8 * DIM + k0, &As[wave*32 + p*8][0]);
        #pragma unroll
        for (int p = 0; p < 2; ++p)
            ASYNC_COPY16(gB + (size_t)p * 8 * DIM + k0, &Bs[wave*16 + p*8][0]);
        __syncthreads();
        #pragma unroll
        for (int ks = 0; ks < 2; ++ks) {
            bf16x8 af[4], bfr[2];
            #pragma unroll
            for (int i = 0; i < 4; ++i)
                af[i] = *reinterpret_cast<const bf16x8*>(&As[wr + i*16 + llo][ks*32 + lhi*8]);
            #pragma unroll
            for (int j = 0; j < 2; ++j)
                bfr[j] = *reinterpret_cast<const bf16x8*>(&Bs[wc + j*16 + llo][ks*32 + lhi*8]);
            __builtin_amdgcn_s_setprio(1);
            #pragma unroll
            for (int i = 0; i < 4; ++i)
                #pragma unroll
                for (int j = 0; j < 2; ++j)
                    acc[i][j] = __builtin_amdgcn_mfma_f32_16x16x32_bf16(af[i], bfr[j], acc[i][j], 0, 0, 0);
            __builtin_amdgcn_s_setprio(0);
        }
        __syncthreads();
    }

    #pragma unroll
    for (int j = 0; j < 2; ++j) {
        int col = n0 + wc + j*16 + llo;
        float bv = bias[col];
        #pragma unroll
        for (int i = 0; i < 4; ++i)
            #pragma unroll
            for (int r = 0; r < 4; ++r) {
                int m = m0 + wr + i*16 + lhi*4 + r;
                out[(size_t)m * DIM + col] = acc[i][j][r] + bv;
            }
    }
}

extern "C" void kernel_launch(void* const* d_in, const int* in_sizes, int n_in,
                              void* d_out, int out_size, void* d_ws, size_t ws_size,
                              hipStream_t stream) {
    const float* x      = (const float*)d_in[0];
    const float* w_qkv  = (const float*)d_in[1];
    const float* b_qkv  = (const float*)d_in[2];
    const float* w_proj = (const float*)d_in[3];
    const float* b_proj = (const float*)d_in[4];
    float* out = (float*)d_out;

    const size_t NX  = (size_t)MTOT * DIM;
    const size_t NWQ = (size_t)3 * DIM * DIM;
    const size_t NWP = (size_t)DIM * DIM;
    const size_t NQ  = (size_t)BATCH * NHEAD * SEQ * HDIM;

    bf16_t* Xb    = (bf16_t*)d_ws;
    bf16_t* Wqkv  = Xb + NX;
    bf16_t* Wproj = Wqkv + NWQ;
    bf16_t* Qb    = Wproj + NWP;
    bf16_t* Kb    = Qb + NQ;
    bf16_t* Vtb   = Kb + NQ;
    bf16_t* AOb   = Vtb + NQ;
    float*  OP    = (float*)(AOb + NQ);
    float*  MS    = OP + 2 * NQ;
    float*  LS    = MS + 2 * 32 * SEQ;

    cvt_kernel<<<(int)((NX + NWQ + NWP) / 1024), 256, 0, stream>>>(x, w_qkv, w_proj, Xb);

    gemm_qkv_kernel<<<768, 256, 0, stream>>>(Xb, Wqkv, b_qkv, Qb, Kb, Vtb);

    attn_split_kernel<<<1024, 256, 0, stream>>>(Qb, Kb, Vtb, OP, MS, LS);

    merge_kernel<<<4096, 256, 0, stream>>>(OP, MS, LS, AOb);

    gemm_proj_kernel<<<512, 256, 0, stream>>>(AOb, Wproj, b_proj, out);
}

// Round 18
// 90.140 us; speedup vs baseline: 3.5951x; 1.1144x over previous
//
#include <hip/hip_runtime.h>

#define DIM 512
#define NHEAD 8
#define HDIM 64
#define BATCH 4
#define SEQ 2048
#define MTOT (BATCH*SEQ)
#define SCALE 0.125f
#define LOG2E 1.4426950408889634f

typedef __bf16 bf16_t;
typedef __bf16 bf16x8 __attribute__((ext_vector_type(8)));
typedef __bf16 bf16x4 __attribute__((ext_vector_type(4)));
typedef __bf16 bf16x2 __attribute__((ext_vector_type(2)));
typedef float f32x4 __attribute__((ext_vector_type(4)));

#define ASYNC_COPY16(g, l) __builtin_amdgcn_global_load_lds( \
    (const __attribute__((address_space(1))) void*)(g),      \
    (__attribute__((address_space(3))) void*)(l), 16, 0, 0)

// ---------------- fused fp32 -> bf16 convert (x | w_qkv | w_proj) ----------------
#define NX_ELEM  (4194304)
#define NWQ_ELEM (786432)
#define NWP_ELEM (262144)
__global__ __launch_bounds__(256) void cvt_kernel(const float* __restrict__ x,
                                                  const float* __restrict__ wq,
                                                  const float* __restrict__ wp,
                                                  bf16_t* __restrict__ out) {
    int i = (blockIdx.x * 256 + threadIdx.x) * 4;
    const float* src;
    if (i < NX_ELEM)                 src = x  + i;
    else if (i < NX_ELEM + NWQ_ELEM) src = wq + (i - NX_ELEM);
    else                             src = wp + (i - NX_ELEM - NWQ_ELEM);
    float4 v = *reinterpret_cast<const float4*>(src);
    bf16x4 o;
    o[0] = (bf16_t)v.x; o[1] = (bf16_t)v.y; o[2] = (bf16_t)v.z; o[3] = (bf16_t)v.w;
    *reinterpret_cast<bf16x4*>(out + i) = o;
}

// ---------------- QKV GEMM: m97 single-buffer; outputs via LDS-transpose coalesced stores ----------------
__global__ __launch_bounds__(256) void gemm_qkv_kernel(
    const bf16_t* __restrict__ X, const bf16_t* __restrict__ W,
    const float* __restrict__ bias,
    bf16_t* __restrict__ Qo, bf16_t* __restrict__ Ko, bf16_t* __restrict__ Vto)
{
    __shared__ bf16_t smem[16384];
    bf16_t (*As)[64] = reinterpret_cast<bf16_t (*)[64]>(smem);
    bf16_t (*Bs)[64] = reinterpret_cast<bf16_t (*)[64]>(smem + 8192);
    unsigned int* Lw = reinterpret_cast<unsigned int*>(smem);
    const int tid = threadIdx.x;
    const int wave = tid >> 6, lane = tid & 63;
    const int lhi = lane >> 4, llo = lane & 15;
    const int o = blockIdx.x;
    const int x = o & 7, i0 = o >> 3;
    const int m0 = (x * 8 + (i0 & 7)) * 128;
    const int n0 = (i0 >> 3) * 128;
    const int wr = (wave >> 1) * 64, wc = (wave & 1) * 64;
    f32x4 acc[4][4] = {};

    const int srow = wave * 32 + (lane >> 3);
    const int scol = (lane & 7) * 8;
    const bf16_t* gA = X + (size_t)(m0 + srow) * DIM + scol;
    const bf16_t* gB = W + (size_t)(n0 + srow) * DIM + scol;

    for (int k0 = 0; k0 < DIM; k0 += 64) {
        #pragma unroll
        for (int p = 0; p < 4; ++p) {
            ASYNC_COPY16(gA + (size_t)p * 8 * DIM + k0, &As[wave*32 + p*8][0]);
            ASYNC_COPY16(gB + (size_t)p * 8 * DIM + k0, &Bs[wave*32 + p*8][0]);
        }
        __syncthreads();
        #pragma unroll
        for (int ks = 0; ks < 2; ++ks) {
            bf16x8 af[4], bfr[4];
            #pragma unroll
            for (int i = 0; i < 4; ++i)
                af[i] = *reinterpret_cast<const bf16x8*>(&As[wr + i*16 + llo][ks*32 + lhi*8]);
            #pragma unroll
            for (int j = 0; j < 4; ++j)
                bfr[j] = *reinterpret_cast<const bf16x8*>(&Bs[wc + j*16 + llo][ks*32 + lhi*8]);
            __builtin_amdgcn_s_setprio(1);
            #pragma unroll
            for (int i = 0; i < 4; ++i)
                #pragma unroll
                for (int j = 0; j < 4; ++j)
                    acc[i][j] = __builtin_amdgcn_mfma_f32_16x16x32_bf16(af[i], bfr[j], acc[i][j], 0, 0, 0);
            __builtin_amdgcn_s_setprio(0);
        }
        __syncthreads();
    }

    const int b = m0 >> 11, ns0 = m0 & 2047;

    if (n0 < 1024) {
        const float qscale = (n0 < 512) ? (SCALE * LOG2E) : 1.0f;
        bf16_t* __restrict__ dst = (n0 < 512) ? Qo : Ko;
        #pragma unroll
        for (int j = 0; j < 4; ++j) {
            int ddc = wc + j*16 + llo;
            float bv = bias[n0 + ddc];
            #pragma unroll
            for (int i = 0; i < 4; ++i)
                #pragma unroll
                for (int r = 0; r < 4; ++r) {
                    int ml = wr + i*16 + lhi*4 + r;
                    smem[ml * 128 + (ddc ^ (((ml >> 2) & 3) * 16))] =
                        (bf16_t)((acc[i][j][r] + bv) * qscale);
                }
        }
        __syncthreads();
        #pragma unroll
        for (int k = 0; k < 8; ++k) {
            int c = tid + k * 256;
            int row = c >> 4, colc = (c & 15) * 8;
            uint4 val = *reinterpret_cast<const uint4*>(
                &smem[row * 128 + (colc ^ (((row >> 2) & 3) * 16))]);
            int col = n0 + colc;
            int hh = (col >> 6) & 7, dd = col & 63;
            size_t bh = (size_t)(b * NHEAD + hh);
            *reinterpret_cast<uint4*>(dst + (bh * SEQ + ns0 + row) * HDIM + dd) = val;
        }
    } else {
        #pragma unroll
        for (int j = 0; j < 4; ++j) {
            int ddc = wc + j*16 + llo;
            float bv = bias[n0 + ddc];
            int xsw = (ddc & 7) * 4;
            #pragma unroll
            for (int i = 0; i < 4; ++i) {
                int dwb = (wr >> 1) + i*8 + lhi*2;
                #pragma unroll
                for (int r2 = 0; r2 < 2; ++r2) {
                    bf16x2 t;
                    t[0] = (bf16_t)(acc[i][j][2*r2]     + bv);
                    t[1] = (bf16_t)(acc[i][j][2*r2 + 1] + bv);
                    Lw[ddc * 64 + ((dwb + r2) ^ xsw)] = __builtin_bit_cast(unsigned int, t);
                }
            }
        }
        __syncthreads();
        const int hh_base = (n0 - 1024) >> 6;
        const int chunk = tid & 15;
        #pragma unroll
        for (int rd = 0; rd < 8; ++rd) {
            int ddc = rd * 16 + (tid >> 4);
            uint4 val = *reinterpret_cast<const uint4*>(
                &Lw[ddc * 64 + ((chunk * 4) ^ ((ddc & 7) * 4))]);
            int dd = ddc & 63;
            int hh = hh_base + (ddc >> 6);
            size_t bh = (size_t)(b * NHEAD + hh);
            *reinterpret_cast<uint4*>(Vto + (bh * HDIM + dd) * SEQ + ns0 + chunk * 8) = val;
        }
    }
}

// ---------------- Flash attention v12: v11 body, 4-wave blocks, 2 independent blocks/CU ----------------
// q-tile 128 (4 waves x 32 q), KVBLK=64, grid 512 -> 2 blocks/CU with
// independent barriers (block A's softmax overlaps block B's LDS/MFMA phases).
__global__ __launch_bounds__(256, 2) void attn_kernel(
    const bf16_t* __restrict__ Q, const bf16_t* __restrict__ K,
    const bf16_t* __restrict__ Vt, bf16_t* __restrict__ O)
{
    __shared__ bf16_t Ks[2][64][64];
    __shared__ bf16_t Vs[2][64][64];
    const int tid = threadIdx.x;
    const int wave = tid >> 6, lane = tid & 63;
    const int lhi = lane >> 4, llo = lane & 15;
    // XCD swizzle: 512 blocks, 64/XCD -> 4 complete bh per XCD (K/V L2-resident)
    const int o = blockIdx.x;
    const int w = (o & 7) * 64 + (o >> 3);
    const int qt = w & 15, bh = w >> 4;
    const bf16_t* Qb = Q + (size_t)bh * SEQ * HDIM;
    const bf16_t* Kb = K + (size_t)bh * SEQ * HDIM;
    const bf16_t* Vb = Vt + (size_t)bh * HDIM * SEQ;
    const int q0 = qt * 128 + wave * 32;

    // staging (256 threads, 2 rows each; (row+32)&7 == row&7 -> same swizzle)
    const int ksr = tid >> 3, kg = tid & 7;             // ksr 0..31
    const int kcol = (kg * 8) ^ ((ksr & 7) * 8);
    const int vd = tid >> 3, vg = tid & 7;              // vd 0..31
    const int pkA = (32*(vg>>2) + 8*((2*vg)&3)   + 4*((vg>>1)&1)) ^ ((vd & 7) * 8);
    const int pkB = (32*(vg>>2) + 8*((2*vg+1)&3) + 4*((vg>>1)&1)) ^ ((vd & 7) * 8);

    bf16x8 aq[2][2];
    #pragma unroll
    for (int qb = 0; qb < 2; ++qb)
        #pragma unroll
        for (int ks = 0; ks < 2; ++ks)
            aq[qb][ks] = *reinterpret_cast<const bf16x8*>(
                Qb + (size_t)(q0 + qb*16 + llo) * HDIM + ks*32 + lhi*8);

    bf16x8 ones;
    #pragma unroll
    for (int e = 0; e < 8; ++e) ones[e] = (bf16_t)1.0f;

    f32x4 acc_o[2][4] = {};
    f32x4 acc_l[2] = {};
    float mstat[2];
    const float THR = 8.0f * LOG2E;
    const int NT = SEQ / 64;

    uint4 kreg0, kreg1, vreg0, vreg1;
    bf16x8 apA[2][2], apB[2][2];
    bf16x8 bvA[2][4], bvB[2][4];

    auto vmax4 = [](const f32x4& v) {
        return fmaxf(fmaxf(v[0], v[1]), fmaxf(v[2], v[3]));
    };

    kreg0 = *reinterpret_cast<const uint4*>(Kb + (size_t)ksr * HDIM + kg*8);
    kreg1 = *reinterpret_cast<const uint4*>(Kb + (size_t)(ksr + 32) * HDIM + kg*8);
    vreg0 = *reinterpret_cast<const uint4*>(Vb + (size_t)vd * SEQ + vg*8);
    vreg1 = *reinterpret_cast<const uint4*>(Vb + (size_t)(vd + 32) * SEQ + vg*8);
    *reinterpret_cast<uint4*>(&Ks[0][ksr][kcol]) = kreg0;
    *reinterpret_cast<uint4*>(&Ks[0][ksr + 32][kcol]) = kreg1;
    *reinterpret_cast<uint2*>(&Vs[0][vd][pkA]) = make_uint2(vreg0.x, vreg0.y);
    *reinterpret_cast<uint2*>(&Vs[0][vd][pkB]) = make_uint2(vreg0.z, vreg0.w);
    *reinterpret_cast<uint2*>(&Vs[0][vd + 32][pkA]) = make_uint2(vreg1.x, vreg1.y);
    *reinterpret_cast<uint2*>(&Vs[0][vd + 32][pkB]) = make_uint2(vreg1.z, vreg1.w);
    __syncthreads();

    kreg0 = *reinterpret_cast<const uint4*>(Kb + (size_t)(64 + ksr) * HDIM + kg*8);
    kreg1 = *reinterpret_cast<const uint4*>(Kb + (size_t)(64 + ksr + 32) * HDIM + kg*8);
    vreg0 = *reinterpret_cast<const uint4*>(Vb + (size_t)vd * SEQ + 64 + vg*8);
    vreg1 = *reinterpret_cast<const uint4*>(Vb + (size_t)(vd + 32) * SEQ + 64 + vg*8);

    {
        f32x4 s[2][4] = {};
        __builtin_amdgcn_s_setprio(1);
        #pragma unroll
        for (int kb = 0; kb < 4; ++kb)
            #pragma unroll
            for (int ks = 0; ks < 2; ++ks) {
                bf16x8 kf = *reinterpret_cast<const bf16x8*>(
                    &Ks[0][kb*16 + llo][(ks*32 + lhi*8) ^ ((llo & 7) * 8)]);
                #pragma unroll
                for (int qb = 0; qb < 2; ++qb)
                    s[qb][kb] = __builtin_amdgcn_mfma_f32_16x16x32_bf16(kf, aq[qb][ks], s[qb][kb], 0, 0, 0);
            }
        __builtin_amdgcn_s_setprio(0);
        #pragma unroll
        for (int qb = 0; qb < 2; ++qb) {
            float mx = fmaxf(fmaxf(vmax4(s[qb][0]), vmax4(s[qb][1])),
                             fmaxf(vmax4(s[qb][2]), vmax4(s[qb][3])));
            mx = fmaxf(mx, __shfl_xor(mx, 16, 64));
            mx = fmaxf(mx, __shfl_xor(mx, 32, 64));
            mstat[qb] = mx;
            #pragma unroll
            for (int kp = 0; kp < 2; ++kp)
                #pragma unroll
                for (int j = 0; j < 4; ++j) {
                    apA[qb][kp][j]     = (bf16_t)__builtin_amdgcn_exp2f(s[qb][2*kp][j]     - mx);
                    apA[qb][kp][4 + j] = (bf16_t)__builtin_amdgcn_exp2f(s[qb][2*kp + 1][j] - mx);
                }
        }
        #pragma unroll
        for (int kp = 0; kp < 2; ++kp)
            #pragma unroll
            for (int qb = 0; qb < 2; ++qb)
                acc_l[qb] = __builtin_amdgcn_mfma_f32_16x16x32_bf16(apA[qb][kp], ones, acc_l[qb], 0, 0, 0);
        #pragma unroll
        for (int kp = 0; kp < 2; ++kp)
            #pragma unroll
            for (int db = 0; db < 4; ++db)
                bvA[kp][db] = *reinterpret_cast<const bf16x8*>(
                    &Vs[0][db*16 + llo][(kp*32 + lhi*8) ^ ((llo & 7) * 8)]);
        *reinterpret_cast<uint4*>(&Ks[1][ksr][kcol]) = kreg0;
        *reinterpret_cast<uint4*>(&Ks[1][ksr + 32][kcol]) = kreg1;
        *reinterpret_cast<uint2*>(&Vs[1][vd][pkA]) = make_uint2(vreg0.x, vreg0.y);
        *reinterpret_cast<uint2*>(&Vs[1][vd][pkB]) = make_uint2(vreg0.z, vreg0.w);
        *reinterpret_cast<uint2*>(&Vs[1][vd + 32][pkA]) = make_uint2(vreg1.x, vreg1.y);
        *reinterpret_cast<uint2*>(&Vs[1][vd + 32][pkB]) = make_uint2(vreg1.z, vreg1.w);
        __syncthreads();
    }

    auto body = [&](int kt, bf16x8 (&apIn)[2][2], bf16x8 (&bvIn)[2][4],
                    bf16x8 (&apOut)[2][2], bf16x8 (&bvOut)[2][4]) {
        const int cur = kt & 1, nxt = cur ^ 1;
        if (kt + 1 < NT) {
            const size_t koff = (size_t)(kt + 1) * 64;
            kreg0 = *reinterpret_cast<const uint4*>(Kb + (koff + ksr) * HDIM + kg*8);
            kreg1 = *reinterpret_cast<const uint4*>(Kb + (koff + ksr + 32) * HDIM + kg*8);
            vreg0 = *reinterpret_cast<const uint4*>(Vb + (size_t)vd * SEQ + koff + vg*8);
            vreg1 = *reinterpret_cast<const uint4*>(Vb + (size_t)(vd + 32) * SEQ + koff + vg*8);
        }
        f32x4 s[2][4] = {};
        __builtin_amdgcn_s_setprio(1);
        #pragma unroll
        for (int kb = 0; kb < 4; ++kb)
            #pragma unroll
            for (int ks = 0; ks < 2; ++ks) {
                bf16x8 kf = *reinterpret_cast<const bf16x8*>(
                    &Ks[cur][kb*16 + llo][(ks*32 + lhi*8) ^ ((llo & 7) * 8)]);
                #pragma unroll
                for (int qb = 0; qb < 2; ++qb)
                    s[qb][kb] = __builtin_amdgcn_mfma_f32_16x16x32_bf16(kf, aq[qb][ks], s[qb][kb], 0, 0, 0);
            }
        __builtin_amdgcn_s_setprio(0);

        float lmax[2];
        bool ok = true;
        #pragma unroll
        for (int qb = 0; qb < 2; ++qb) {
            float mx = fmaxf(fmaxf(vmax4(s[qb][0]), vmax4(s[qb][1])),
                             fmaxf(vmax4(s[qb][2]), vmax4(s[qb][3])));
            lmax[qb] = mx;
            ok &= (mx <= mstat[qb] + THR);
        }
        if (!__all(ok)) {
            #pragma unroll
            for (int kp = 0; kp < 2; ++kp)
                #pragma unroll
                for (int db = 0; db < 4; ++db)
                    #pragma unroll
                    for (int qb = 0; qb < 2; ++qb)
                        acc_o[qb][db] = __builtin_amdgcn_mfma_f32_16x16x32_bf16(apIn[qb][kp], bvIn[kp][db], acc_o[qb][db], 0, 0, 0);
            #pragma unroll
            for (int kp = 0; kp < 2; ++kp)
                #pragma unroll
                for (int db = 0; db < 4; ++db)
                    #pragma unroll
                    for (int e = 0; e < 8; ++e) bvIn[kp][db][e] = (bf16_t)0.f;
            #pragma unroll
            for (int qb = 0; qb < 2; ++qb) {
                float mx = lmax[qb];
                mx = fmaxf(mx, __shfl_xor(mx, 16, 64));
                mx = fmaxf(mx, __shfl_xor(mx, 32, 64));
                float mold = mstat[qb];
                float mn = fmaxf(mold, mx);
                float alpha = __builtin_amdgcn_exp2f(mold - mn);
                mstat[qb] = mn;
                #pragma unroll
                for (int r = 0; r < 4; ++r) {
                    float av = __shfl(alpha, (lane & 48) >> 2 | r, 64);
                    acc_l[qb][r] *= av;
                    #pragma unroll
                    for (int db = 0; db < 4; ++db) acc_o[qb][db][r] *= av;
                }
            }
        }

        __builtin_amdgcn_s_setprio(1);
        #pragma unroll
        for (int kp = 0; kp < 2; ++kp) {
            #pragma unroll
            for (int qb = 0; qb < 2; ++qb)
                #pragma unroll
                for (int j = 0; j < 4; ++j) {
                    apOut[qb][kp][j]     = (bf16_t)__builtin_amdgcn_exp2f(s[qb][2*kp][j]     - mstat[qb]);
                    apOut[qb][kp][4 + j] = (bf16_t)__builtin_amdgcn_exp2f(s[qb][2*kp + 1][j] - mstat[qb]);
                }
            #pragma unroll
            for (int db = 0; db < 4; ++db)
                #pragma unroll
                for (int qb = 0; qb < 2; ++qb)
                    acc_o[qb][db] = __builtin_amdgcn_mfma_f32_16x16x32_bf16(apIn[qb][kp], bvIn[kp][db], acc_o[qb][db], 0, 0, 0);
            #pragma unroll
            for (int qb = 0; qb < 2; ++qb)
                acc_l[qb] = __builtin_amdgcn_mfma_f32_16x16x32_bf16(apOut[qb][kp], ones, acc_l[qb], 0, 0, 0);
        }
        __builtin_amdgcn_s_setprio(0);

        #pragma unroll
        for (int kp = 0; kp < 2; ++kp)
            #pragma unroll
            for (int db = 0; db < 4; ++db)
                bvOut[kp][db] = *reinterpret_cast<const bf16x8*>(
                    &Vs[cur][db*16 + llo][(kp*32 + lhi*8) ^ ((llo & 7) * 8)]);

        if (kt + 1 < NT) {
            *reinterpret_cast<uint4*>(&Ks[nxt][ksr][kcol]) = kreg0;
            *reinterpret_cast<uint4*>(&Ks[nxt][ksr + 32][kcol]) = kreg1;
            *reinterpret_cast<uint2*>(&Vs[nxt][vd][pkA]) = make_uint2(vreg0.x, vreg0.y);
            *reinterpret_cast<uint2*>(&Vs[nxt][vd][pkB]) = make_uint2(vreg0.z, vreg0.w);
            *reinterpret_cast<uint2*>(&Vs[nxt][vd + 32][pkA]) = make_uint2(vreg1.x, vreg1.y);
            *reinterpret_cast<uint2*>(&Vs[nxt][vd + 32][pkB]) = make_uint2(vreg1.z, vreg1.w);
        }
        __syncthreads();
    };

    for (int tp = 1; tp + 1 < NT; tp += 2) {
        body(tp,     apA, bvA, apB, bvB);
        body(tp + 1, apB, bvB, apA, bvA);
    }
    body(NT - 1, apA, bvA, apB, bvB);

    #pragma unroll
    for (int kp = 0; kp < 2; ++kp)
        #pragma unroll
        for (int db = 0; db < 4; ++db)
            #pragma unroll
            for (int qb = 0; qb < 2; ++qb)
                acc_o[qb][db] = __builtin_amdgcn_mfma_f32_16x16x32_bf16(apB[qb][kp], bvB[kp][db], acc_o[qb][db], 0, 0, 0);

    const int b = bh >> 3, h = bh & 7;
    #pragma unroll
    for (int qb = 0; qb < 2; ++qb) {
        #pragma unroll
        for (int r = 0; r < 4; ++r) {
            float iv = 1.0f / acc_l[qb][r];
            int q = q0 + qb*16 + lhi*4 + r;
            #pragma unroll
            for (int db = 0; db < 4; ++db)
                O[(size_t)(b * SEQ + q) * DIM + h*HDIM + db*16 + llo] =
                    (bf16_t)(acc_o[qb][db][r] * iv);
        }
    }
}

// ---------------- Output proj GEMM: m97, 128x64 tiles, grid 512 (2 blocks/CU) ----------------
__global__ __launch_bounds__(256) void gemm_proj_kernel(
    const bf16_t* __restrict__ X, const bf16_t* __restrict__ W,
    const float* __restrict__ bias, float* __restrict__ out)
{
    __shared__ bf16_t As[128][64];
    __shared__ bf16_t Bs[64][64];
    const int tid = threadIdx.x;
    const int wave = tid >> 6, lane = tid & 63;
    const int lhi = lane >> 4, llo = lane & 15;
    const int o = blockIdx.x;
    const int x = o & 7, i0 = o >> 3;
    const int m0 = (x * 8 + (i0 & 7)) * 128;
    const int n0 = (i0 >> 3) * 64;
    const int wr = (wave >> 1) * 64, wc = (wave & 1) * 32;
    f32x4 acc[4][2] = {};

    const int srow = wave * 32 + (lane >> 3);
    const int srowB = wave * 16 + (lane >> 3);
    const int scol = (lane & 7) * 8;
    const bf16_t* gA = X + (size_t)(m0 + srow) * DIM + scol;
    const bf16_t* gB = W + (size_t)(n0 + srowB) * DIM + scol;

    for (int k0 = 0; k0 < DIM; k0 += 64) {
        #pragma unroll
        for (int p = 0; p < 4; ++p)
            ASYNC_COPY16(gA + (size_t)p * 8 * DIM + k0, &As[wave*32 + p*8][0]);
        #pragma unroll
        for (int p = 0; p < 2; ++p)
            ASYNC_COPY16(gB + (size_t)p * 8 * DIM + k0, &Bs[wave*16 + p*8][0]);
        __syncthreads();
        #pragma unroll
        for (int ks = 0; ks < 2; ++ks) {
            bf16x8 af[4], bfr[2];
            #pragma unroll
            for (int i = 0; i < 4; ++i)
                af[i] = *reinterpret_cast<const bf16x8*>(&As[wr + i*16 + llo][ks*32 + lhi*8]);
            #pragma unroll
            for (int j = 0; j < 2; ++j)
                bfr[j] = *reinterpret_cast<const bf16x8*>(&Bs[wc + j*16 + llo][ks*32 + lhi*8]);
            __builtin_amdgcn_s_setprio(1);
            #pragma unroll
            for (int i = 0; i < 4; ++i)
                #pragma unroll
                for (int j = 0; j < 2; ++j)
                    acc[i][j] = __builtin_amdgcn_mfma_f32_16x16x32_bf16(af[i], bfr[j], acc[i][j], 0, 0, 0);
            __builtin_amdgcn_s_setprio(0);
        }
        __syncthreads();
    }

    #pragma unroll
    for (int j = 0; j < 2; ++j) {
        int col = n0 + wc + j*16 + llo;
        float bv = bias[col];
        #pragma unroll
        for (int i = 0; i < 4; ++i)
            #pragma unroll
            for (int r = 0; r < 4; ++r) {
                int m = m0 + wr + i*16 + lhi*4 + r;
                out[(size_t)m * DIM + col] = acc[i][j][r] + bv;
            }
    }
}

extern "C" void kernel_launch(void* const* d_in, const int* in_sizes, int n_in,
                              void* d_out, int out_size, void* d_ws, size_t ws_size,
                              hipStream_t stream) {
    const float* x      = (const float*)d_in[0];
    const float* w_qkv  = (const float*)d_in[1];
    const float* b_qkv  = (const float*)d_in[2];
    const float* w_proj = (const float*)d_in[3];
    const float* b_proj = (const float*)d_in[4];
    float* out = (float*)d_out;

    const size_t NX  = (size_t)MTOT * DIM;
    const size_t NWQ = (size_t)3 * DIM * DIM;
    const size_t NWP = (size_t)DIM * DIM;
    const size_t NQ  = (size_t)BATCH * NHEAD * SEQ * HDIM;

    bf16_t* Xb    = (bf16_t*)d_ws;
    bf16_t* Wqkv  = Xb + NX;
    bf16_t* Wproj = Wqkv + NWQ;
    bf16_t* Qb    = Wproj + NWP;
    bf16_t* Kb    = Qb + NQ;
    bf16_t* Vtb   = Kb + NQ;
    bf16_t* AOb   = Vtb + NQ;

    cvt_kernel<<<(int)((NX + NWQ + NWP) / 1024), 256, 0, stream>>>(x, w_qkv, w_proj, Xb);

    gemm_qkv_kernel<<<768, 256, 0, stream>>>(Xb, Wqkv, b_qkv, Qb, Kb, Vtb);

    attn_kernel<<<512, 256, 0, stream>>>(Qb, Kb, Vtb, AOb);

    gemm_proj_kernel<<<512, 256, 0, stream>>>(AOb, Wproj, b_proj, out);
}